// Round 13
// baseline (205.334 us; speedup 1.0000x reference)
//
#include <hip/hip_runtime.h>
#include <hip/hip_bf16.h>
#include <math.h>

// ---------------------------------------------------------------------------
// AdderNet LeNet forward. R13: fc1 j-tiled x4 — R12 post-mortem showed fc1's
// 500 blocks each streaming ALL of featMM (819KB) = 409MB L2 traffic + a
// serial 400-load chain per thread (VALUBusy 18%). Now block = 4 j rows:
// feat loads amortized 4x (L2 traffic -> 102MB), 16 accumulators (4j x 4r)
// of chain 100 each. Grid 125 blocks x 256 thr (128 b x 2 khalf).
// adder1 / adder2 / fc2 unchanged from R12 (proven, absmax 4.9e-4).
// ---------------------------------------------------------------------------

#define B_N 128
#define EPSBN 1e-5f

// ---- adder1 + BN1 slot partials + w2t fold ---------------------------------
__global__ __launch_bounds__(256) void adder1_bn_kernel(
    const float* __restrict__ x, const float* __restrict__ w1,
    const float* __restrict__ w2,
    float* __restrict__ out, float* __restrict__ slots1,  // [40][720]
    float* __restrict__ w2t) {                            // [20][25][64]
  __shared__ float csum[40];
  const int tid = threadIdx.x;
  if (tid < 40) csum[tid] = 0.f;
  __syncthreads();
  int idx = blockIdx.x * 256 + tid;   // 184320 = 720*256
  int owc = idx % 3; int t = idx / 3;
  int oh  = t % 24;  t /= 24;
  int o   = t % 20;  int b = t / 20;
  const float* xb = x + b * 784;
  const float* wb = w1 + o * 25;
  float acc[8];
#pragma unroll
  for (int i = 0; i < 8; ++i) acc[i] = 0.f;
#pragma unroll
  for (int kh = 0; kh < 5; ++kh) {
    float xr[12];
    const float4* xp = (const float4*)(xb + (oh + kh) * 28 + owc * 8);
#pragma unroll
    for (int i = 0; i < 3; ++i) {
      float4 v = xp[i];
      xr[4*i] = v.x; xr[4*i+1] = v.y; xr[4*i+2] = v.z; xr[4*i+3] = v.w;
    }
    float wr[5];
#pragma unroll
    for (int i = 0; i < 5; ++i) wr[i] = wb[kh * 5 + i];
#pragma unroll
    for (int ow = 0; ow < 8; ++ow)
#pragma unroll
      for (int kw = 0; kw < 5; ++kw)
        acc[ow] += fabsf(xr[ow + kw] - wr[kw]);
  }
  float* op = out + (((size_t)b * 20 + o) * 24 + oh) * 24 + owc * 8;
  float4 s0 = { -acc[0], -acc[1], -acc[2], -acc[3] };
  float4 s1 = { -acc[4], -acc[5], -acc[6], -acc[7] };
  *(float4*)(op)     = s0;
  *(float4*)(op + 4) = s1;
  float s = 0.f, s2 = 0.f;
#pragma unroll
  for (int i = 0; i < 8; ++i) { s -= acc[i]; s2 += acc[i] * acc[i]; }
  atomicAdd(&csum[o * 2],     s);
  atomicAdd(&csum[o * 2 + 1], s2);
  __syncthreads();
  if (tid < 40) slots1[tid * 720 + blockIdx.x] = csum[tid];  // transposed

  // w2t fold: blocks 0-124 transpose w2[50,20,5,5] -> w2t[c][k][o(64)]
  if (blockIdx.x < 125) {
    int i = blockIdx.x * 256 + tid;   // < 32000
    int oo = i & 63, tt = i >> 6, k = tt % 25, c = tt / 25;
    w2t[i] = (oo < 50) ? w2[oo * 500 + c * 25 + k] : 0.f;
  }
}

// ---- adder2: BN1 finalize (vectorized slot reduce) + pooled LDS staging ----
// + compute + minmax pool epilogue + BN2 slot stores.
__global__ __launch_bounds__(256) void adder2_bn_kernel(
    const float* __restrict__ h1, const float* __restrict__ slots1,
    const float* __restrict__ g1, const float* __restrict__ be1,
    const float* __restrict__ w2t,
    float2* __restrict__ featMM,        // [800][128] of {max,min}
    float* __restrict__ slots2) {       // [100][512]
  __shared__ float lh[1440];    // [c][6 rows][12]
  __shared__ float sbb[40];     // BN1 (scale,bias)
  __shared__ float red[240];    // [elem e][seg]
  __shared__ float csum[100];
  const int tid = threadIdx.x;
  if (tid < 100) csum[tid] = 0.f;

  // BN1 finalize: slots1[e][720] reduced as 6 x 120 contiguous (30 float4)
  if (tid < 240) {
    int e = tid / 6, seg = tid - 6 * (tid / 6);
    const float4* sp = (const float4*)(slots1 + e * 720 + seg * 120);
    float r = 0.f;
#pragma unroll
    for (int i = 0; i < 30; ++i) {
      float4 v = sp[i];
      r += (v.x + v.y) + (v.z + v.w);
    }
    red[e * 6 + seg] = r;
  }
  __syncthreads();
  if (tid < 20) {
    float sm = 0.f, s2 = 0.f;
#pragma unroll
    for (int sgi = 0; sgi < 6; ++sgi) {
      sm += red[(2 * tid) * 6 + sgi];
      s2 += red[(2 * tid + 1) * 6 + sgi];
    }
    const float inv_n = 1.f / (B_N * 576);
    float mean = sm * inv_n;
    float var  = s2 * inv_n - mean * mean;
    float sc   = g1[tid] * rsqrtf(var + EPSBN);
    sbb[2 * tid]     = sc;
    sbb[2 * tid + 1] = be1[tid] - mean * sc;
  }
  __syncthreads();

  const int oq = blockIdx.x & 3;
  const int b  = blockIdx.x >> 2;   // 512 blocks = 128 b * 4 oq

  // stage: lh[c][r][col] = BN1+pool of h1[b][c][4oq+2r ..+1][2col ..+1]
  {
    const float* hb = h1 + (size_t)b * 11520;   // 20*24*24
    for (int j = tid; j < 1440; j += 256) {
      int c = j / 72, rem = j - c * 72;
      int r = rem / 12, col = rem - r * 12;
      const float* hp = hb + (c * 24 + (4 * oq + 2 * r)) * 24 + 2 * col;
      float2 r0 = *(const float2*)(hp);
      float2 r1 = *(const float2*)(hp + 24);
      float sc = sbb[2 * c], bi = sbb[2 * c + 1];
      float v0 = fmaf(sc, r0.x, bi);
      float v1 = fmaf(sc, r0.y, bi);
      float v2 = fmaf(sc, r1.x, bi);
      float v3 = fmaf(sc, r1.y, bi);
      lh[j] = fmaxf(fmaxf(v0, v1), fmaxf(v2, v3));
    }
  }
  __syncthreads();

  const int o   = tid >> 2;           // 0..63 (active < 50)
  const int q   = tid & 3;
  const int ohl = q >> 1;
  const int owh = q & 1;
  if (o < 50) {
    float acc[4];
#pragma unroll
    for (int i = 0; i < 4; ++i) acc[i] = 0.f;
    for (int c = 0; c < 20; ++c) {
      const float* lc = lh + c * 72 + owh * 4;
      const float* wc = w2t + c * 1600 + o;
#pragma unroll
      for (int kh = 0; kh < 5; ++kh) {
        float hr[8];
        const float* lp = lc + (ohl + kh) * 12;
        *(float4*)(hr)     = *(const float4*)(lp);
        *(float4*)(hr + 4) = *(const float4*)(lp + 4);
        float wr[5];
#pragma unroll
        for (int i = 0; i < 5; ++i) wr[i] = wc[(kh * 5 + i) * 64];
#pragma unroll
        for (int ow = 0; ow < 4; ++ow)
#pragma unroll
          for (int kw = 0; kw < 5; ++kw)
            acc[ow] += fabsf(hr[ow + kw] - wr[kw]);
      }
    }
    float v0 = -acc[0], v1 = -acc[1], v2 = -acc[2], v3 = -acc[3];
    float s  = v0 + v1 + v2 + v3;
    float s2 = v0*v0 + v1*v1 + v2*v2 + v3*v3;
    atomicAdd(&csum[o * 2],     s);
    atomicAdd(&csum[o * 2 + 1], s2);
    float pM0 = fmaxf(v0, v1), pM1 = fmaxf(v2, v3);
    float pm0 = fminf(v0, v1), pm1 = fminf(v2, v3);
    float qM0 = fmaxf(pM0, __shfl_xor(pM0, 2));
    float qM1 = fmaxf(pM1, __shfl_xor(pM1, 2));
    float qm0 = fminf(pm0, __shfl_xor(pm0, 2));
    float qm1 = fminf(pm1, __shfl_xor(pm1, 2));
    if (ohl == 0) {
      int k0 = o * 16 + oq * 4 + owh * 2;   // featT index k = c*16+ph*4+pw
      featMM[(size_t)k0 * 128 + b]       = make_float2(qM0, qm0);
      featMM[(size_t)(k0 + 1) * 128 + b] = make_float2(qM1, qm1);
    }
  }
  __syncthreads();
  if (tid < 100) slots2[tid * 512 + blockIdx.x] = csum[tid];  // transposed
}

// ---- fc1 + relu, BN2 finalize inline, 4-j tile ----------------------------
// block = jt (125): computes j0..j0+3; 256 thr = 128 b x 2 khalf; each feat
// load feeds 4 j accumulators (16 chains of length 100).
__global__ __launch_bounds__(256) void fc1_kernel(
    const float2* __restrict__ featMM, const float* __restrict__ slots2,
    const float* __restrict__ g2, const float* __restrict__ be2,
    const float* __restrict__ w1, const float* __restrict__ b1,
    float* __restrict__ hid) {
  __shared__ float sb2[100];    // BN2 (scale,bias)
  __shared__ float red2[200];   // [elem e][half]
  __shared__ float part[4][256];
  const int tid = threadIdx.x;
  // BN2 finalize: slots2[e][512] reduced as 2 x 256 contiguous (64 float4)
  if (tid < 200) {
    int e = tid >> 1, half = tid & 1;
    const float4* sp = (const float4*)(slots2 + e * 512 + half * 256);
    float r = 0.f;
#pragma unroll
    for (int i = 0; i < 64; ++i) {
      float4 v = sp[i];
      r += (v.x + v.y) + (v.z + v.w);
    }
    red2[e * 2 + half] = r;
  }
  __syncthreads();
  if (tid < 50) {
    float sm = red2[(2 * tid) * 2]     + red2[(2 * tid) * 2 + 1];
    float s2 = red2[(2 * tid + 1) * 2] + red2[(2 * tid + 1) * 2 + 1];
    const float inv_n = 1.f / (B_N * 64);
    float mean = sm * inv_n;
    float var  = s2 * inv_n - mean * mean;
    float sc   = g2[tid] * rsqrtf(var + EPSBN);
    sb2[2 * tid]     = sc;
    sb2[2 * tid + 1] = be2[tid] - mean * sc;
  }
  __syncthreads();

  const int j0 = blockIdx.x * 4;
  const int b = tid & 127;
  const int khalf = tid >> 7;
  const float* wr0 = w1 + (size_t)(j0 + 0) * 800;
  const float* wr1 = w1 + (size_t)(j0 + 1) * 800;
  const float* wr2 = w1 + (size_t)(j0 + 2) * 800;
  const float* wr3 = w1 + (size_t)(j0 + 3) * 800;
  float acc[4][4];   // [jj][qr]
#pragma unroll
  for (int a = 0; a < 4; ++a)
#pragma unroll
    for (int c = 0; c < 4; ++c) acc[a][c] = 0.f;

  for (int kg = khalf * 25; kg < khalf * 25 + 25; ++kg) {
    float sc = sb2[2 * kg], bi = sb2[2 * kg + 1];   // channel c == kg
    int kbase = kg * 16;
#pragma unroll
    for (int r = 0; r < 16; r += 4) {
      int kk = kbase + r;
      float2 f0 = featMM[(size_t)(kk    ) * 128 + b];
      float2 f1 = featMM[(size_t)(kk + 1) * 128 + b];
      float2 f2 = featMM[(size_t)(kk + 2) * 128 + b];
      float2 f3 = featMM[(size_t)(kk + 3) * 128 + b];
      float e0 = fmaf(sc, sc > 0.f ? f0.x : f0.y, bi);
      float e1 = fmaf(sc, sc > 0.f ? f1.x : f1.y, bi);
      float e2 = fmaf(sc, sc > 0.f ? f2.x : f2.y, bi);
      float e3 = fmaf(sc, sc > 0.f ? f3.x : f3.y, bi);
      float4 wa = *(const float4*)(wr0 + kk);   // wave-uniform
      float4 wb = *(const float4*)(wr1 + kk);
      float4 wc = *(const float4*)(wr2 + kk);
      float4 wd = *(const float4*)(wr3 + kk);
      const int qr = r >> 2;
      acc[0][qr] = fmaf(e0, wa.x, fmaf(e1, wa.y, fmaf(e2, wa.z, fmaf(e3, wa.w, acc[0][qr]))));
      acc[1][qr] = fmaf(e0, wb.x, fmaf(e1, wb.y, fmaf(e2, wb.z, fmaf(e3, wb.w, acc[1][qr]))));
      acc[2][qr] = fmaf(e0, wc.x, fmaf(e1, wc.y, fmaf(e2, wc.z, fmaf(e3, wc.w, acc[2][qr]))));
      acc[3][qr] = fmaf(e0, wd.x, fmaf(e1, wd.y, fmaf(e2, wd.z, fmaf(e3, wd.w, acc[3][qr]))));
    }
  }
#pragma unroll
  for (int jj = 0; jj < 4; ++jj)
    part[jj][tid] = (acc[jj][0] + acc[jj][1]) + (acc[jj][2] + acc[jj][3]);
  __syncthreads();
  if (tid < 128) {
#pragma unroll
    for (int jj = 0; jj < 4; ++jj)
      hid[tid * 512 + j0 + jj] =
          fmaxf(b1[j0 + jj] + part[jj][tid] + part[jj][tid + 128], 0.f);
  }
}

// ---- fc2 + bias + softmax: hid[128][512] x w[10,500] -> out[128][10] -------
__global__ __launch_bounds__(64) void fc2_softmax_kernel(
    const float* __restrict__ hid, const float* __restrict__ w2,
    const float* __restrict__ b2, float* __restrict__ out) {
  const int b = blockIdx.x, lane = threadIdx.x;
  const float* hb = hid + b * 512;
  __shared__ float logit[16];
  float hv[8];
#pragma unroll
  for (int i = 0; i < 8; ++i) {
    int k = lane + 64 * i;
    hv[i] = (k < 500) ? hb[k] : 0.f;
  }
  for (int j = 0; j < 10; ++j) {
    const float* wr = w2 + j * 500;
    float acc = 0.f;
#pragma unroll
    for (int i = 0; i < 8; ++i) {
      int k = lane + 64 * i;
      float w = (k < 500) ? wr[k] : 0.f;
      acc = fmaf(hv[i], w, acc);
    }
#pragma unroll
    for (int off = 32; off > 0; off >>= 1) acc += __shfl_down(acc, off);
    if (lane == 0) logit[j] = acc + b2[j];
  }
  __syncthreads();
  if (lane == 0) {
    float m = logit[0];
    for (int j = 1; j < 10; ++j) m = fmaxf(m, logit[j]);
    float s = 0.f, e[10];
    for (int j = 0; j < 10; ++j) { e[j] = __expf(logit[j] - m); s += e[j]; }
    float inv = 1.f / s;
    for (int j = 0; j < 10; ++j) out[b * 10 + j] = e[j] * inv;
  }
}

extern "C" void kernel_launch(void* const* d_in, const int* in_sizes, int n_in,
                              void* d_out, int out_size, void* d_ws, size_t ws_size,
                              hipStream_t stream) {
  const float* x   = (const float*)d_in[0];   // [128,1,28,28]
  const float* w1  = (const float*)d_in[1];   // [20,1,5,5]
  const float* g1  = (const float*)d_in[2];   // [20]
  const float* be1 = (const float*)d_in[3];   // [20]
  const float* w2  = (const float*)d_in[4];   // [50,20,5,5]
  const float* g2  = (const float*)d_in[5];   // [50]
  const float* be2 = (const float*)d_in[6];   // [50]
  const float* fw1 = (const float*)d_in[7];   // [500,800]
  const float* fb1 = (const float*)d_in[8];   // [500]
  const float* fw2 = (const float*)d_in[9];   // [10,500]
  const float* fb2 = (const float*)d_in[10];  // [10]
  float* out = (float*)d_out;

  // workspace (floats) — all disjoint, nothing needs pre-zeroing; 16B-aligned
  float*  ws     = (float*)d_ws;
  float*  h1     = ws;                      // 1474560 = 128*20*24*24
  float*  slots1 = ws + 1843200;            // 40*720  = 28800
  float*  slots2 = ws + 1872000;            // 100*512 = 51200
  float*  w2t    = ws + 1923200;            // 32000
  float2* featMM = (float2*)(ws + 1955200); // 800*128 float2 = 204800 floats
  float*  hid    = ws + 2160000;            // 128*512

  adder1_bn_kernel<<<720, 256, 0, stream>>>(x, w1, w2, h1, slots1, w2t);
  adder2_bn_kernel<<<512, 256, 0, stream>>>(h1, slots1, g1, be1, w2t,
                                            featMM, slots2);
  fc1_kernel<<<125, 256, 0, stream>>>(featMM, slots2, g2, be2, fw1, fb1, hid);
  fc2_softmax_kernel<<<128, 64, 0, stream>>>(hid, fw2, fb2, out);
}

// Round 14
// 141.588 us; speedup vs baseline: 1.4502x; 1.4502x over previous
//
#include <hip/hip_runtime.h>
#include <hip/hip_bf16.h>
#include <math.h>

// ---------------------------------------------------------------------------
// AdderNet LeNet forward. R14: R10 champion structure (6 dispatches, 141.8us)
// + fc1 k-quad packing. R13 lesson: fc1 is load-instruction-latency bound at
// fixed parallelism — so keep 500 blocks and halve its load instructions:
// bn_pool_t writes featT4[kq][b][4] so fc1 loads 4 k per dwordx4 (coalesced
// 16B/lane). All other kernels byte-identical to R10.
// ---------------------------------------------------------------------------

#define B_N 128
#define EPSBN 1e-5f
#define NCOPY 16

// ---- prep: w2t[c][k][o(64)] transpose + zero sums --------------------------
__global__ __launch_bounds__(256) void prep_kernel(
    const float* __restrict__ w2, float* __restrict__ w2t,
    float* __restrict__ sums) {
  int idx = blockIdx.x * 256 + threadIdx.x;   // 134*256 = 34304
  if (idx < 32000) {
    int o = idx & 63, t = idx >> 6, k = t % 25, c = t / 25;
    w2t[idx] = (o < 50) ? w2[o * 500 + c * 25 + k] : 0.f;
  } else {
    int j = idx - 32000;
    if (j < NCOPY * 140) sums[j] = 0.f;
  }
}

// ---- adder1 + BN1 partials: x[128,1,28,28], w[20,1,5,5] -> h1[128,20,24,24]
__global__ __launch_bounds__(256) void adder1_bn_kernel(
    const float* __restrict__ x, const float* __restrict__ w1,
    float* __restrict__ out, float* __restrict__ sums) {  // sums[NCOPY*40]
  __shared__ float csum[40];
  if (threadIdx.x < 40) csum[threadIdx.x] = 0.f;
  __syncthreads();
  int idx = blockIdx.x * 256 + threadIdx.x;   // 184320 = 720*256
  int owc = idx % 3; int t = idx / 3;
  int oh  = t % 24;  t /= 24;
  int o   = t % 20;  int b = t / 20;
  const float* xb = x + b * 784;
  const float* wb = w1 + o * 25;
  float acc[8];
#pragma unroll
  for (int i = 0; i < 8; ++i) acc[i] = 0.f;
#pragma unroll
  for (int kh = 0; kh < 5; ++kh) {
    float xr[12];
    const float4* xp = (const float4*)(xb + (oh + kh) * 28 + owc * 8);
#pragma unroll
    for (int i = 0; i < 3; ++i) {
      float4 v = xp[i];
      xr[4*i] = v.x; xr[4*i+1] = v.y; xr[4*i+2] = v.z; xr[4*i+3] = v.w;
    }
    float wr[5];
#pragma unroll
    for (int i = 0; i < 5; ++i) wr[i] = wb[kh * 5 + i];
#pragma unroll
    for (int ow = 0; ow < 8; ++ow)
#pragma unroll
      for (int kw = 0; kw < 5; ++kw)
        acc[ow] += fabsf(xr[ow + kw] - wr[kw]);
  }
  float* op = out + (((size_t)b * 20 + o) * 24 + oh) * 24 + owc * 8;
  float4 s0 = { -acc[0], -acc[1], -acc[2], -acc[3] };
  float4 s1 = { -acc[4], -acc[5], -acc[6], -acc[7] };
  *(float4*)(op)     = s0;
  *(float4*)(op + 4) = s1;
  float s = 0.f, s2 = 0.f;
#pragma unroll
  for (int i = 0; i < 8; ++i) { s -= acc[i]; s2 += acc[i] * acc[i]; }
  atomicAdd(&csum[o * 2],     s);
  atomicAdd(&csum[o * 2 + 1], s2);
  __syncthreads();
  if (threadIdx.x < 40) {
    float v = csum[threadIdx.x];
    if (v != 0.f)
      atomicAdd(&sums[(blockIdx.x & (NCOPY - 1)) * 40 + threadIdx.x], v);
  }
}

// ---- adder2 + fused BN1-finalize/pool staging + BN2 partials ---------------
__global__ __launch_bounds__(256) void adder2_bn_kernel(
    const float* __restrict__ h1, const float* __restrict__ sums1,
    const float* __restrict__ g1, const float* __restrict__ be1,
    const float* __restrict__ w2t,
    float* __restrict__ out, float* __restrict__ sums2) { // sums2[NCOPY*100]
  __shared__ float lh[1440];    // [c][6 rows][12]
  __shared__ float sb[40];      // (scale,bias) per channel
  __shared__ float csum[100];
  const int tid = threadIdx.x;
  if (tid < 100) csum[tid] = 0.f;
  if (tid < 20) {
    float sm = 0.f, s2 = 0.f;
#pragma unroll
    for (int cp = 0; cp < NCOPY; ++cp) {
      sm += sums1[cp * 40 + 2 * tid];
      s2 += sums1[cp * 40 + 2 * tid + 1];
    }
    const float inv_n = 1.f / (B_N * 576);
    float mean = sm * inv_n;
    float var  = s2 * inv_n - mean * mean;
    float sc   = g1[tid] * rsqrtf(var + EPSBN);
    sb[2 * tid]     = sc;
    sb[2 * tid + 1] = be1[tid] - mean * sc;
  }
  __syncthreads();

  const int oq = blockIdx.x & 3;
  const int b  = blockIdx.x >> 2;   // 512 blocks = 128 b * 4 oq

  // stage: lh[c][r][col] = BN+pool of h1[b][c][4oq+2r .. +1][2col .. +1]
  {
    const float* hb = h1 + (size_t)b * 11520;   // 20*24*24
    for (int j = tid; j < 1440; j += 256) {
      int c = j / 72, rem = j - c * 72;
      int r = rem / 12, col = rem - r * 12;
      const float* hp = hb + (c * 24 + (4 * oq + 2 * r)) * 24 + 2 * col;
      float2 r0 = *(const float2*)(hp);
      float2 r1 = *(const float2*)(hp + 24);
      float sc = sb[2 * c], bi = sb[2 * c + 1];
      float v0 = fmaf(sc, r0.x, bi);
      float v1 = fmaf(sc, r0.y, bi);
      float v2 = fmaf(sc, r1.x, bi);
      float v3 = fmaf(sc, r1.y, bi);
      lh[j] = fmaxf(fmaxf(v0, v1), fmaxf(v2, v3));
    }
  }
  __syncthreads();

  const int o   = tid >> 2;
  const int q   = tid & 3;
  const int ohl = q >> 1;
  const int owh = q & 1;
  if (o < 50) {
    float acc[4];
#pragma unroll
    for (int i = 0; i < 4; ++i) acc[i] = 0.f;
    for (int c = 0; c < 20; ++c) {
      const float* lc = lh + c * 72 + owh * 4;
      const float* wc = w2t + c * 1600 + o;
#pragma unroll
      for (int kh = 0; kh < 5; ++kh) {
        float hr[8];
        const float* lp = lc + (ohl + kh) * 12;
        *(float4*)(hr)     = *(const float4*)(lp);
        *(float4*)(hr + 4) = *(const float4*)(lp + 4);
        float wr[5];
#pragma unroll
        for (int i = 0; i < 5; ++i) wr[i] = wc[(kh * 5 + i) * 64];
#pragma unroll
        for (int ow = 0; ow < 4; ++ow)
#pragma unroll
          for (int kw = 0; kw < 5; ++kw)
            acc[ow] += fabsf(hr[ow + kw] - wr[kw]);
      }
    }
    const int oh = 2 * oq + ohl;
    float4 st = { -acc[0], -acc[1], -acc[2], -acc[3] };
    *(float4*)(out + (((size_t)b * 50 + o) * 8 + oh) * 8 + owh * 4) = st;
    float s = 0.f, s2 = 0.f;
#pragma unroll
    for (int i = 0; i < 4; ++i) { s -= acc[i]; s2 += acc[i] * acc[i]; }
    atomicAdd(&csum[o * 2],     s);
    atomicAdd(&csum[o * 2 + 1], s2);
  }
  __syncthreads();
  if (tid < 100)
    atomicAdd(&sums2[(blockIdx.x & (NCOPY - 1)) * 100 + tid], csum[tid]);
}

// ---- BN2 finalize + apply + 2x2 maxpool, k-quad packed featT4 --------------
// h:[128,50,8,8] -> featT4[(k>>2)][b][k&3], k = c*16+ph*4+pw
__global__ __launch_bounds__(256) void bn_pool_t_kernel(
    const float* __restrict__ h, const float* __restrict__ sums,
    const float* __restrict__ gamma, const float* __restrict__ beta,
    float* __restrict__ featT4, float inv_n) {
  int idx = blockIdx.x * 256 + threadIdx.x;    // 102400 = 400*256
  int pw = idx % 4; int t = idx / 4;
  int ph = t % 4;   t /= 4;
  int c  = t % 50;  int b = t / 50;
  float sm = 0.f, s2 = 0.f;
#pragma unroll
  for (int cp = 0; cp < NCOPY; ++cp) {
    sm += sums[cp * 100 + 2 * c];
    s2 += sums[cp * 100 + 2 * c + 1];
  }
  float mean = sm * inv_n;
  float var  = s2 * inv_n - mean * mean;
  float sc   = gamma[c] * rsqrtf(var + EPSBN);
  float bi   = beta[c] - mean * sc;
  const float* hp = h + ((b * 50 + c) * 8 + 2 * ph) * 8 + 2 * pw;
  float2 r0 = *(const float2*)(hp);
  float2 r1 = *(const float2*)(hp + 8);
  float v0 = fmaf(sc, r0.x, bi);
  float v1 = fmaf(sc, r0.y, bi);
  float v2 = fmaf(sc, r1.x, bi);
  float v3 = fmaf(sc, r1.y, bi);
  int kq = c * 4 + ph;          // k-quad index; pw = k&3
  featT4[(kq * 128 + b) * 4 + pw] = fmaxf(fmaxf(v0, v1), fmaxf(v2, v3));
}

// ---- fc1 + relu: featT4 x w[500,800] -> hid[128][512] ----------------------
// block = j (500); 256 thr = 128 b x 2 k-halves; per iter one dwordx4 feat
// (4 k, coalesced 16B/lane) + one wave-uniform dwordx4 w.
__global__ __launch_bounds__(256) void fc1_kernel(
    const float* __restrict__ featT4, const float* __restrict__ w1,
    const float* __restrict__ b1, float* __restrict__ hid) {
  const int j = blockIdx.x;
  const int b = threadIdx.x & 127;
  const int khalf = threadIdx.x >> 7;
  const float* wr = w1 + j * 800;
  float a0 = 0.f, a1 = 0.f, a2 = 0.f, a3 = 0.f;
  int q0 = khalf * 100;
  for (int qi = q0; qi < q0 + 100; ++qi) {
    float4 f  = *(const float4*)(featT4 + (size_t)(qi * 128 + b) * 4);
    float4 w4 = *(const float4*)(wr + qi * 4);   // wave-uniform
    a0 = fmaf(f.x, w4.x, a0);
    a1 = fmaf(f.y, w4.y, a1);
    a2 = fmaf(f.z, w4.z, a2);
    a3 = fmaf(f.w, w4.w, a3);
  }
  __shared__ float part[256];
  part[threadIdx.x] = (a0 + a1) + (a2 + a3);
  __syncthreads();
  if (threadIdx.x < 128)
    hid[b * 512 + j] =
        fmaxf(b1[j] + part[threadIdx.x] + part[threadIdx.x + 128], 0.f);
}

// ---- fc2 + bias + softmax: hid[128][512] x w[10,500] -> out[128][10] -------
__global__ __launch_bounds__(64) void fc2_softmax_kernel(
    const float* __restrict__ hid, const float* __restrict__ w2,
    const float* __restrict__ b2, float* __restrict__ out) {
  const int b = blockIdx.x, lane = threadIdx.x;
  const float* hb = hid + b * 512;
  __shared__ float logit[16];
  float hv[8];
#pragma unroll
  for (int i = 0; i < 8; ++i) {
    int k = lane + 64 * i;
    hv[i] = (k < 500) ? hb[k] : 0.f;
  }
  for (int j = 0; j < 10; ++j) {
    const float* wr = w2 + j * 500;
    float acc = 0.f;
#pragma unroll
    for (int i = 0; i < 8; ++i) {
      int k = lane + 64 * i;
      float w = (k < 500) ? wr[k] : 0.f;
      acc = fmaf(hv[i], w, acc);
    }
#pragma unroll
    for (int off = 32; off > 0; off >>= 1) acc += __shfl_down(acc, off);
    if (lane == 0) logit[j] = acc + b2[j];
  }
  __syncthreads();
  if (lane == 0) {
    float m = logit[0];
    for (int j = 1; j < 10; ++j) m = fmaxf(m, logit[j]);
    float s = 0.f, e[10];
    for (int j = 0; j < 10; ++j) { e[j] = __expf(logit[j] - m); s += e[j]; }
    float inv = 1.f / s;
    for (int j = 0; j < 10; ++j) out[b * 10 + j] = e[j] * inv;
  }
}

extern "C" void kernel_launch(void* const* d_in, const int* in_sizes, int n_in,
                              void* d_out, int out_size, void* d_ws, size_t ws_size,
                              hipStream_t stream) {
  const float* x   = (const float*)d_in[0];   // [128,1,28,28]
  const float* w1  = (const float*)d_in[1];   // [20,1,5,5]
  const float* g1  = (const float*)d_in[2];   // [20]
  const float* be1 = (const float*)d_in[3];   // [20]
  const float* w2  = (const float*)d_in[4];   // [50,20,5,5]
  const float* g2  = (const float*)d_in[5];   // [50]
  const float* be2 = (const float*)d_in[6];   // [50]
  const float* fw1 = (const float*)d_in[7];   // [500,800]
  const float* fb1 = (const float*)d_in[8];   // [500]
  const float* fw2 = (const float*)d_in[9];   // [10,500]
  const float* fb2 = (const float*)d_in[10];  // [10]
  float* out = (float*)d_out;

  // workspace layout (floats) — ALL DISJOINT (ws ~268MB; no reuse games).
  float* ws     = (float*)d_ws;
  float* h1     = ws;               // [0, 1474560)         128*20*24*24
  float* sums1  = ws + 1843200;     // NCOPY*40   = 640
  float* sums2  = ws + 1843840;     // NCOPY*100  = 1600
  float* w2t    = ws + 1845504;     // 32000
  float* h2     = ws + 1900000;     // 409600     128*50*8*8
  float* featT4 = ws + 2310000;     // 102400     [200][128][4]
  float* hid    = ws + 2420000;     // 65536      128*512

  prep_kernel<<<134, 256, 0, stream>>>(w2, w2t, sums1);  // zeros sums1+sums2
  adder1_bn_kernel<<<720, 256, 0, stream>>>(x, w1, h1, sums1);
  adder2_bn_kernel<<<512, 256, 0, stream>>>(h1, sums1, g1, be1, w2t, h2, sums2);
  bn_pool_t_kernel<<<400, 256, 0, stream>>>(h2, sums2, g2, be2, featT4,
                                            1.f / (B_N * 64));
  fc1_kernel<<<500, 256, 0, stream>>>(featT4, fw1, fb1, hid);
  fc2_softmax_kernel<<<128, 64, 0, stream>>>(hid, fw2, fb2, out);
}